// Round 13
// baseline (949.402 us; speedup 1.0000x reference)
//
#include <hip/hip_runtime.h>
#include <hip/hip_bf16.h>
#include <math.h>

typedef unsigned short u16;
typedef __attribute__((ext_vector_type(8))) short bf16x8;
typedef __attribute__((ext_vector_type(4))) float f32x4;
typedef __attribute__((ext_vector_type(4))) u16 u16x4;
typedef __attribute__((ext_vector_type(4))) unsigned u32x4;

#define T_SEQ 1024
#define HDIM  2048
#define NHEAD 8
#define NKVH  4
#define HSZ   256
#define ISZ   8192
#define NVOC  32000

#define GLDS(src, dst) __builtin_amdgcn_global_load_lds( \
    (const __attribute__((address_space(1))) void*)(src), \
    (__attribute__((address_space(3))) void*)(dst), 16, 0, 0)

__device__ __forceinline__ u16 f2bf(float f) {
    union { float f; unsigned u; } v; v.f = f;
    return (u16)((v.u + 0x7fffu + ((v.u >> 16) & 1u)) >> 16);
}
__device__ __forceinline__ float bf2f(u16 h) {
    union { unsigned u; float f; } v; v.u = (unsigned)h << 16; return v.f;
}

__device__ __forceinline__ unsigned cvt_pk_bf16(float a, float b) {
    unsigned r;
    asm("v_cvt_pk_bf16_f32 %0, %1, %2" : "=v"(r) : "v"(a), "v"(b));
    return r;
}

__device__ __forceinline__ float fast_tanh(float x) {
    float e = __expf(-2.0f * fabsf(x));
    float t = (1.0f - e) / (1.0f + e);
    return copysignf(t, x);
}

__device__ __forceinline__ f32x4 mfma16(bf16x8 a, bf16x8 b, f32x4 c) {
    return __builtin_amdgcn_mfma_f32_16x16x32_bf16(a, b, c, 0, 0, 0);
}

// ============================================================================
// gemm_r: C = A[M,K](bf16) * B[N,K](f32 -> bf16 via reg-stage)^T
// BM=256 BN=128 BK=64, 512 thr = 8 waves (4M x 2N), per-wave 64x64
// (gemm_dp/gemm_f verified fragment + epilogue math).
// LDS: 3 slots x (A bf16 32K + B bf16 16K) = 147456 B. Inner loop pure bf16:
// 8 A + 8 B ds_read_b128/wave (vs gemm_f's 8+16 w/ f32 B) -> LDS traffic
// per K-tile ~1400cy vs MFMA ~1030cy (was ~2050cy).
// Schedule per K-tile (ONE barrier):
//   [vmcnt(top); lgkmcnt(0); barrier]
//   issue A-DMA(kt+2) -> slot (kt+2)%3 ; issue B-f32 glb->reg (kt+2)
//   [vmcnt(mid)]  -> drains B-regs(kt+1) (keeps kt+2's 8 ops in flight)
//   cvt_pk + swizzled ds_write B(kt+1) -> slot (kt+1)%3
//   ds_read A(kt),B(kt) slot kt%3 ; 32 MFMA
// Slot roles distinct mod 3; cross-iter write-vs-read separated by barrier.
// top/mid = 8 steady (never 0 until tail). R-buffers unrolled x2 (rule #20).
// Swizzle both paths: granule g of row r at slot g^(r&7) (A via pre-swizzled
// DMA source; B via swizzled ds_write addr). KT must be even, >= 4.
// EPI: 0=f32, 1=tanh-cap-30, 2=bf16(gelu_tanh(acc)*UP[idx]).
// ============================================================================
template<int EPI, typename CT>
__global__ __launch_bounds__(512, 1)
void gemm_r(const u16* __restrict__ A, int lda,
            const float* __restrict__ B, int ldb,
            CT* __restrict__ C, int ldc, long sC, int K,
            const float* __restrict__ UP)
{
    extern __shared__ char lds[];   // 3 * 49152 bytes
    const int t = threadIdx.x;
    const int lane = t & 63, wid = t >> 6;
    const int z = blockIdx.z;
    A += (long)z * K;
    B += (long)z * K;
    C += (long)z * sC;

    // XCD-aware bijective remap (m204), m-fastest within chunk
    const int nwg = gridDim.x * gridDim.y;
    int flat = blockIdx.y * gridDim.x + blockIdx.x;
    {
        const int q = nwg >> 3, r = nwg & 7;
        const int xcd = flat & 7, loc = flat >> 3;
        flat = (xcd < r ? xcd * (q + 1) : r * (q + 1) + (xcd - r) * q) + loc;
    }
    const int gm = gridDim.y;
    const long m0 = (long)(flat % gm) * 256;
    const long n0 = (long)(flat / gm) * 128;

    // A staging (DMA): 4 ops x 64 rows; row t>>3, granule t&7, key r&7
    const int ar = t >> 3;
    const int asl = ((t & 7) ^ (ar & 7)) * 8;          // bf16 elems
    const u16* gA0 = A + (m0 + ar)       * (long)lda + asl;
    const u16* gA1 = A + (m0 + 64 + ar)  * (long)lda + asl;
    const u16* gA2 = A + (m0 + 128 + ar) * (long)lda + asl;
    const u16* gA3 = A + (m0 + 192 + ar) * (long)lda + asl;

    auto stageA = [&](int kt) {
        const long ko = (long)kt * 64;
        char* d = lds + (kt % 3) * 49152 + t * 16;
        GLDS(gA0 + ko, d);
        GLDS(gA1 + ko, d + 8192);
        GLDS(gA2 + ko, d + 16384);
        GLDS(gA3 + ko, d + 24576);
    };

    // B reg staging: rows r0 = t>>3, r1 = 64+(t>>3); granule g = t&7
    // (8 consecutive f32 at col g*8) -> coalesced 128B lines
    const int bg = t & 7;
    const float* gB = B + (n0 + (t >> 3)) * (long)ldb + bg * 8;
    const long b64 = 64L * ldb;

    auto loadB = [&](int kt, f32x4 (&R)[4]) {
        const float* p = gB + (long)kt * 64;
        R[0] = *(const f32x4*)(p);
        R[1] = *(const f32x4*)(p + 4);
        R[2] = *(const f32x4*)(p + b64);
        R[3] = *(const f32x4*)(p + b64 + 4);
    };
    auto commitB = [&](int kt, f32x4 (&R)[4]) {
        u16* bb = (u16*)(lds + (kt % 3) * 49152 + 32768);
        const int r0 = t >> 3, r1 = 64 + (t >> 3);
        const int sl = (bg ^ (r0 & 7)) * 8;            // r1&7 == r0&7
        u32x4 w0, w1;
        w0.x = cvt_pk_bf16(R[0].x, R[0].y);
        w0.y = cvt_pk_bf16(R[0].z, R[0].w);
        w0.z = cvt_pk_bf16(R[1].x, R[1].y);
        w0.w = cvt_pk_bf16(R[1].z, R[1].w);
        w1.x = cvt_pk_bf16(R[2].x, R[2].y);
        w1.y = cvt_pk_bf16(R[2].z, R[2].w);
        w1.z = cvt_pk_bf16(R[3].x, R[3].y);
        w1.w = cvt_pk_bf16(R[3].z, R[3].w);
        *(u32x4*)(bb + r0 * 64 + sl) = w0;
        *(u32x4*)(bb + r1 * 64 + sl) = w1;
    };

    f32x4 acc[4][4] = {};
    const int fr = lane & 15, kq = lane >> 4;
    const int wm = wid >> 1, wn = wid & 1;
    const int ps0 = ((kq)     ^ (fr & 7)) * 8;
    const int ps1 = ((4 + kq) ^ (fr & 7)) * 8;
    const int KT = K >> 6;

    auto compute = [&](int kt) {
        const u16* As   = (const u16*)(lds + (kt % 3) * 49152);
        const u16* Bs16 = As + 16384;
        const int arow = wm * 64 + fr;
        const int brow = wn * 64 + fr;
        #pragma unroll
        for (int kk = 0; kk < 2; ++kk) {
            const int ps = kk ? ps1 : ps0;
            bf16x8 af[4], bfv[4];
            #pragma unroll
            for (int mi = 0; mi < 4; ++mi)
                af[mi] = *(const bf16x8*)(As + (arow + mi * 16) * 64 + ps);
            #pragma unroll
            for (int ni = 0; ni < 4; ++ni)
                bfv[ni] = *(const bf16x8*)(Bs16 + (brow + ni * 16) * 64 + ps);
            __builtin_amdgcn_s_setprio(1);
            #pragma unroll
            for (int mi = 0; mi < 4; ++mi)
                #pragma unroll
                for (int ni = 0; ni < 4; ++ni)
                    acc[mi][ni] = mfma16(af[mi], bfv[ni], acc[mi][ni]);
            __builtin_amdgcn_s_setprio(0);
        }
    };

    f32x4 R0[4], R1[4];
    // prologue: Bg(0)->R0, A(0), A(1), Bg(1)->R1 ; drain Bg(0) ; commit slot0
    loadB(0, R0);
    stageA(0);
    stageA(1);
    loadB(1, R1);
    asm volatile("s_waitcnt vmcnt(12)" ::: "memory");
    commitB(0, R0);

    auto step = [&](int kt, f32x4 (&Rld)[4], f32x4 (&Rcm)[4]) {
        if (kt + 2 < KT) asm volatile("s_waitcnt vmcnt(8)" ::: "memory");
        else             asm volatile("s_waitcnt vmcnt(0)" ::: "memory");
        asm volatile("s_waitcnt lgkmcnt(0)" ::: "memory");
        __builtin_amdgcn_s_barrier();
        if (kt + 2 < KT) { stageA(kt + 2); loadB(kt + 2, Rld); }
        if (kt + 1 < KT) {
            if (kt + 3 < KT) asm volatile("s_waitcnt vmcnt(8)" ::: "memory");
            else             asm volatile("s_waitcnt vmcnt(0)" ::: "memory");
            commitB(kt + 1, Rcm);
        }
        compute(kt);
    };

    for (int kt = 0; kt < KT; kt += 2) {   // KT even (>= 4) at all call sites
        step(kt,     R0, R1);
        step(kt + 1, R1, R0);
    }

    const int crb = kq * 4, ccol = fr;
    #pragma unroll
    for (int mi = 0; mi < 4; ++mi) {
        #pragma unroll
        for (int rr = 0; rr < 4; ++rr) {
            const long row = m0 + wm * 64 + mi * 16 + crb + rr;
            CT* cp = C + row * ldc + n0 + wn * 64 + ccol;
            #pragma unroll
            for (int ni = 0; ni < 4; ++ni) {
                float v = acc[mi][ni][rr];
                if constexpr (EPI == 1) {
                    cp[ni * 16] = (CT)(fast_tanh(v * (1.0f / 30.0f)) * 30.0f);
                } else if constexpr (EPI == 2) {
                    const float* upp = UP + row * (long)ldc + n0 + wn * 64 + ccol;
                    const float tt = fast_tanh(0.79788456f * (v + 0.044715f * v * v * v));
                    const float g = 0.5f * v * (1.0f + tt);
                    ((u16*)cp)[ni * 16] = f2bf(g * upp[ni * 16]);
                } else {
                    cp[ni * 16] = (CT)v;
                }
            }
        }
    }
}

// ---- 128x128 GEMM for attention, with mask-skip / K-trim ----
template<int EPI, typename CT>
__global__ __launch_bounds__(256)
void gemm_bt(const u16* __restrict__ A, int lda, long sA,
             const u16* __restrict__ B, int ldb, long sB, int bshift,
             CT* __restrict__ C, int ldc, long sC, int K,
             int swin, int tflag)
{
    __shared__ u16 As[128 * 32];
    __shared__ u16 Bs[128 * 32];
    const int tid = threadIdx.x;
    const int lane = tid & 63, wid = tid >> 6;
    const int z = blockIdx.z;
    A += (long)z * sA;
    B += (long)(z >> bshift) * sB;
    C += (long)z * sC;

    const int nwg = gridDim.x * gridDim.y;
    int flat = blockIdx.y * gridDim.x + blockIdx.x;
    {
        const int q = nwg >> 3, r = nwg & 7;
        const int xcd = flat & 7, loc = flat >> 3;
        flat = (xcd < r ? xcd * (q + 1) : r * (q + 1) + (xcd - r) * q) + loc;
    }
    const int gm = gridDim.y;
    const long m0 = (long)(flat % gm) * 128;
    const long n0 = (long)(flat / gm) * 128;

    if (swin > 0) {
        if (n0 > m0 + 127) return;
        if (m0 - (n0 + 127) >= swin) return;
    }
    int klo = 0, khi = K;
    if (tflag > 0) {
        const long hi = m0 + 128;
        if (hi < khi) khi = (int)hi;
        const long lo = m0 - (long)tflag + 1;
        klo = lo > 0 ? (int)(lo & ~31L) : 0;
    }

    f32x4 acc[4][4] = {};

    const int ar = tid >> 2, ac = (tid & 3) * 8;
    const u16* gA0 = A + (m0 + ar) * lda + ac;
    const u16* gB0 = B + (n0 + ar) * (long)ldb + ac;
    const long a64 = 64L * lda, b64 = 64L * ldb;

    const int fr = lane & 15, fk = (lane >> 4) * 8;
    const int wm = (wid >> 1) * 64, wn = (wid & 1) * 64;

    for (int k0 = klo; k0 < khi; k0 += 32) {
        GLDS(gA0 + k0,       &As[tid * 8]);
        GLDS(gA0 + a64 + k0, &As[2048 + tid * 8]);
        GLDS(gB0 + k0,       &Bs[tid * 8]);
        GLDS(gB0 + b64 + k0, &Bs[2048 + tid * 8]);
        __syncthreads();
        bf16x8 af[4], bfv[4];
        #pragma unroll
        for (int mi = 0; mi < 4; ++mi)
            af[mi] = *(const bf16x8*)(&As[(wm + mi * 16 + fr) * 32 + fk]);
        #pragma unroll
        for (int ni = 0; ni < 4; ++ni)
            bfv[ni] = *(const bf16x8*)(&Bs[(wn + ni * 16 + fr) * 32 + fk]);
        #pragma unroll
        for (int mi = 0; mi < 4; ++mi)
            #pragma unroll
            for (int ni = 0; ni < 4; ++ni)
                acc[mi][ni] = mfma16(af[mi], bfv[ni], acc[mi][ni]);
        __syncthreads();
    }

    const int crb = (lane >> 4) * 4, ccol = lane & 15;
    #pragma unroll
    for (int mi = 0; mi < 4; ++mi) {
        #pragma unroll
        for (int rr = 0; rr < 4; ++rr) {
            const long row = m0 + wm + mi * 16 + crb + rr;
            CT* cp = C + row * ldc + n0 + wn + ccol;
            #pragma unroll
            for (int ni = 0; ni < 4; ++ni) {
                float v = acc[mi][ni][rr];
                if (EPI == 1) v = fast_tanh(v * (1.0f / 30.0f)) * 30.0f;
                if constexpr (sizeof(CT) == 2) cp[ni * 16] = f2bf(v);
                else                           cp[ni * 16] = v;
            }
        }
    }
}

// ---- embedding lookup * sqrt(H) ----
__global__ __launch_bounds__(256)
void embed_scale(const int* __restrict__ tok, const float* __restrict__ emb,
                 float* __restrict__ x)
{
    const int t = blockIdx.x, tid = threadIdx.x;
    const long src = (long)tok[t] * HDIM;
    f32x4 a = *(const f32x4*)(emb + src + tid * 8);
    f32x4 b = *(const f32x4*)(emb + src + tid * 8 + 4);
    a *= 45.254834f; b *= 45.254834f;
    *(f32x4*)(x + (long)t * HDIM + tid * 8) = a;
    *(f32x4*)(x + (long)t * HDIM + tid * 8 + 4) = b;
}

__device__ __forceinline__ float block_sum(float v, float* red) {
    #pragma unroll
    for (int o = 32; o; o >>= 1) v += __shfl_xor(v, o);
    const int tid = threadIdx.x;
    if ((tid & 63) == 0) red[tid >> 6] = v;
    __syncthreads();
    return red[0] + red[1] + red[2] + red[3];
}

// ---- rmsnorm (f32 in) -> bf16 out ----
__global__ __launch_bounds__(256)
void rmsnorm_bf16(const float* __restrict__ x, const float* __restrict__ w,
                  u16* __restrict__ out)
{
    __shared__ float red[4];
    const int t = blockIdx.x, tid = threadIdx.x;
    const float* row = x + (long)t * HDIM;
    f32x4 a = *(const f32x4*)(row + tid * 8);
    f32x4 b = *(const f32x4*)(row + tid * 8 + 4);
    float ss = a.x*a.x + a.y*a.y + a.z*a.z + a.w*a.w
             + b.x*b.x + b.y*b.y + b.z*b.z + b.w*b.w;
    ss = block_sum(ss, red);
    const float r = rsqrtf(ss * (1.0f / HDIM) + 1e-6f);
    f32x4 wa = *(const f32x4*)(w + tid * 8);
    f32x4 wb = *(const f32x4*)(w + tid * 8 + 4);
    u16x4 o0, o1;
    o0.x = f2bf(a.x * r * (1.0f + wa.x)); o0.y = f2bf(a.y * r * (1.0f + wa.y));
    o0.z = f2bf(a.z * r * (1.0f + wa.z)); o0.w = f2bf(a.w * r * (1.0f + wa.w));
    o1.x = f2bf(b.x * r * (1.0f + wb.x)); o1.y = f2bf(b.y * r * (1.0f + wb.y));
    o1.z = f2bf(b.z * r * (1.0f + wb.z)); o1.w = f2bf(b.w * r * (1.0f + wb.w));
    *(u16x4*)(out + (long)t * HDIM + tid * 8) = o0;
    *(u16x4*)(out + (long)t * HDIM + tid * 8 + 4) = o1;
}

// ---- x += rmsnorm(sum_s y[s], w) ----
__global__ __launch_bounds__(256)
void add_rmsnorm(float* __restrict__ x, const float* __restrict__ y,
                 const float* __restrict__ w, int nsplit, long stride)
{
    __shared__ float red[4];
    const int t = blockIdx.x, tid = threadIdx.x;
    const float* yr = y + (long)t * HDIM;
    f32x4 a = *(const f32x4*)(yr + tid * 8);
    f32x4 b = *(const f32x4*)(yr + tid * 8 + 4);
    for (int s = 1; s < nsplit; ++s) {
        a += *(const f32x4*)(yr + s * stride + tid * 8);
        b += *(const f32x4*)(yr + s * stride + tid * 8 + 4);
    }
    float ss = a.x*a.x + a.y*a.y + a.z*a.z + a.w*a.w
             + b.x*b.x + b.y*b.y + b.z*b.z + b.w*b.w;
    ss = block_sum(ss, red);
    const float r = rsqrtf(ss * (1.0f / HDIM) + 1e-6f);
    f32x4 wa = *(const f32x4*)(w + tid * 8);
    f32x4 wb = *(const f32x4*)(w + tid * 8 + 4);
    float* xr = x + (long)t * HDIM;
    f32x4 xa = *(const f32x4*)(xr + tid * 8);
    f32x4 xb = *(const f32x4*)(xr + tid * 8 + 4);
    xa.x += a.x * r * (1.0f + wa.x); xa.y += a.y * r * (1.0f + wa.y);
    xa.z += a.z * r * (1.0f + wa.z); xa.w += a.w * r * (1.0f + wa.w);
    xb.x += b.x * r * (1.0f + wb.x); xb.y += b.y * r * (1.0f + wb.y);
    xb.z += b.z * r * (1.0f + wb.z); xb.w += b.w * r * (1.0f + wb.w);
    *(f32x4*)(xr + tid * 8) = xa;
    *(f32x4*)(xr + tid * 8 + 4) = xb;
}

#define QKV_STRIDE (1024L * 4096)

// ---- rope + split (qkv = sum of 2 split-K slices): q(bf16,*SCALE), k(bf16) ----
__global__ __launch_bounds__(256)
void qkv_post(const float* __restrict__ qkv, u16* __restrict__ qb,
              u16* __restrict__ kb)
{
    const int t = blockIdx.x, tid = threadIdx.x;
    const float* row = qkv + (long)t * 4096;
    const float ft = (float)t;
    #pragma unroll
    for (int it = 0; it < 4; ++it) {
        const int p = tid + it * 256;
        const int nh = p >> 7, d = p & 127;
        const float inv = powf(10000.0f, -(float)d * (1.0f / 128.0f));
        const float ang = ft * inv;
        const float c = cosf(ang), s = sinf(ang);
        const int i1 = nh * 256 + d, i2 = i1 + 128;
        const float x1 = row[i1] + row[i1 + QKV_STRIDE];
        const float x2 = row[i2] + row[i2 + QKV_STRIDE];
        const long ob = ((long)nh * T_SEQ + t) * HSZ;
        qb[ob + d]       = f2bf((x1 * c - x2 * s) * 0.0625f);
        qb[ob + 128 + d] = f2bf((x1 * s + x2 * c) * 0.0625f);
    }
    #pragma unroll
    for (int it = 0; it < 2; ++it) {
        const int p = tid + it * 256;
        const int kv = p >> 7, d = p & 127;
        const float inv = powf(10000.0f, -(float)d * (1.0f / 128.0f));
        const float ang = ft * inv;
        const float c = cosf(ang), s = sinf(ang);
        const int i1 = 2048 + kv * 256 + d, i2 = i1 + 128;
        const float x1 = row[i1] + row[i1 + QKV_STRIDE];
        const float x2 = row[i2] + row[i2 + QKV_STRIDE];
        const long ob = ((long)kv * T_SEQ + t) * HSZ;
        kb[ob + d]       = f2bf(x1 * c - x2 * s);
        kb[ob + 128 + d] = f2bf(x1 * s + x2 * c);
    }
}

// ---- V (summed 2 slices) -> vT[kv][d][t] bf16, tiled transpose ----
__global__ __launch_bounds__(256)
void v_transpose(const float* __restrict__ qkvb, u16* __restrict__ vT)
{
    __shared__ u16 tile[64][65];
    const int t0 = blockIdx.x * 64, d0 = blockIdx.y * 64, kv = blockIdx.z;
    const int lane = threadIdx.x & 63, w = threadIdx.x >> 6;
    #pragma unroll
    for (int i = 0; i < 16; ++i) {
        const int t = w * 16 + i;
        const long idx = (long)(t0 + t) * 4096 + 3072 + kv * 256 + d0 + lane;
        tile[t][lane] = f2bf(qkvb[idx] + qkvb[idx + QKV_STRIDE]);
    }
    __syncthreads();
    #pragma unroll
    for (int i = 0; i < 16; ++i) {
        const int d = w * 16 + i;
        vT[((long)kv * HSZ + d0 + d) * T_SEQ + t0 + lane] = tile[lane][d];
    }
}

// ---- softcap + mask + softmax -> bf16 probs ----
__global__ __launch_bounds__(256)
void softmax_mask(const float* __restrict__ sc, u16* __restrict__ pr, int win)
{
    __shared__ float redm[4], reds[4];
    const int i = blockIdx.x, h = blockIdx.y, tid = threadIdx.x;
    const long base = ((long)h * T_SEQ + i) * T_SEQ;
    f32x4 sv = *(const f32x4*)(sc + base + tid * 4);
    float vals[4];
    #pragma unroll
    for (int j = 0; j < 4; ++j) {
        const int col = tid * 4 + j;
        const float s = fast_tanh(sv[j] * 0.02f) * 50.0f;
        const bool valid = (col <= i) && ((i - col) < win);
        vals[j] = valid ? s : -3.0e38f;
    }
    float m = fmaxf(fmaxf(vals[0], vals[1]), fmaxf(vals[2], vals[3]));
    #pragma unroll
    for (int o = 32; o; o >>= 1) m = fmaxf(m, __shfl_xor(m, o));
    if ((tid & 63) == 0) redm[tid >> 6] = m;
    __syncthreads();
    m = fmaxf(fmaxf(redm[0], redm[1]), fmaxf(redm[2], redm[3]));
    float sum = 0.0f;
    #pragma unroll
    for (int j = 0; j < 4; ++j) { vals[j] = __expf(vals[j] - m); sum += vals[j]; }
    #pragma unroll
    for (int o = 32; o; o >>= 1) sum += __shfl_xor(sum, o);
    if ((tid & 63) == 0) reds[tid >> 6] = sum;
    __syncthreads();
    sum = reds[0] + reds[1] + reds[2] + reds[3];
    const float inv = 1.0f / sum;
    u16x4 o4;
    #pragma unroll
    for (int j = 0; j < 4; ++j) o4[j] = f2bf(vals[j] * inv);
    *(u16x4*)(pr + base + tid * 4) = o4;
}

extern "C" void kernel_launch(void* const* d_in, const int* in_sizes, int n_in,
                              void* d_out, int out_size, void* d_ws, size_t ws_size,
                              hipStream_t stream)
{
    (void)in_sizes; (void)n_in; (void)out_size; (void)ws_size;
    const int*   tokens = (const int*)  d_in[0];
    const float* emb    = (const float*)d_in[1];
    const float* qkv_w  = (const float*)d_in[2];
    const float* o_w    = (const float*)d_in[3];
    const float* gate_w = (const float*)d_in[4];
    const float* up_w   = (const float*)d_in[5];
    const float* down_w = (const float*)d_in[6];
    const float* ln_in  = (const float*)d_in[7];
    const float* ln_pa  = (const float*)d_in[8];
    const float* ln_pre = (const float*)d_in[9];
    const float* ln_post= (const float*)d_in[10];
    const float* ln_f   = (const float*)d_in[11];
    float* logits = (float*)d_out;

    char* base = (char*)d_ws;
    size_t off = 0;
    auto alloc = [&](size_t b) { char* p = base + off; off += (b + 255) & ~(size_t)255; return p; };

    float* x    = (float*)alloc((size_t)T_SEQ * HDIM * 4);
    u16*   hb   = (u16*)  alloc((size_t)T_SEQ * HDIM * 2);
    u16*   qb   = (u16*)  alloc((size_t)NHEAD * T_SEQ * HSZ * 2);
    u16*   kb   = (u16*)  alloc((size_t)NKVH * T_SEQ * HSZ * 2);
    u16*   vT   = (u16*)  alloc((size_t)NKVH * HSZ * T_SEQ * 2);
    u16*   ao   = (u16*)  alloc((size_t)T_SEQ * HDIM * 2);
    u16*   pb   = (u16*)  alloc((size_t)T_SEQ * ISZ * 2);
    // big aliased region (64MB), sequential lifetimes:
    //  qkv partials[2] -> sc+pr -> o partials[4] -> ub -> down partials[4]
    char*  big  = alloc((size_t)2 * T_SEQ * ISZ * 4);
    float* P    = (float*)big;
    float* sc   = (float*)big;
    u16*   pr   = (u16*)(big + (size_t)NHEAD * T_SEQ * T_SEQ * 4);
    float* ub   = (float*)(big + (size_t)T_SEQ * ISZ * 4);

    const size_t LDSR = 3 * 49152;   // gemm_r dynamic LDS
    const long s2048 = 1024L * 2048;
    const int BIGWIN = 1 << 29;

    embed_scale<<<T_SEQ, 256, 0, stream>>>(tokens, emb, x);
    for (int l = 0; l < 2; ++l) {
        const int win = (l == 0) ? 512 : BIGWIN;
        rmsnorm_bf16<<<T_SEQ, 256, 0, stream>>>(x, ln_in + l * HDIM, hb);
        gemm_r<0, float><<<dim3(32, 4, 2), 512, LDSR, stream>>>(
            hb, HDIM, qkv_w + (size_t)l * 4096 * HDIM, HDIM, P, 4096, QKV_STRIDE, 1024, ub);
        qkv_post<<<T_SEQ, 256, 0, stream>>>(P, qb, kb);
        v_transpose<<<dim3(16, 4, 4), 256, 0, stream>>>(P, vT);
        gemm_bt<0, float><<<dim3(8, 8, NHEAD), 256, 0, stream>>>(
            qb, HSZ, (long)T_SEQ * HSZ, kb, HSZ, (long)T_SEQ * HSZ, 1,
            sc, T_SEQ, (long)T_SEQ * T_SEQ, HSZ, win, 0);
        softmax_mask<<<dim3(T_SEQ, NHEAD, 1), 256, 0, stream>>>(
            sc, pr, l == 0 ? 512 : (1 << 30));
        gemm_bt<0, u16><<<dim3(2, 8, NHEAD), 256, 0, stream>>>(
            pr, T_SEQ, (long)T_SEQ * T_SEQ, vT, T_SEQ, (long)HSZ * T_SEQ, 1,
            ao, HDIM, (long)HSZ, T_SEQ, 0, win);
        gemm_r<0, float><<<dim3(16, 4, 4), 512, LDSR, stream>>>(
            ao, HDIM, o_w + (size_t)l * HDIM * HDIM, HDIM, P, HDIM, s2048, 512, ub);
        add_rmsnorm<<<T_SEQ, 256, 0, stream>>>(x, P, ln_pa + l * HDIM, 4, s2048);
        rmsnorm_bf16<<<T_SEQ, 256, 0, stream>>>(x, ln_pre + l * HDIM, hb);
        // up first (f32 -> ub), then gate with fused gelu(acc)*ub -> pb (bf16)
        gemm_r<0, float><<<dim3(64, 4, 1), 512, LDSR, stream>>>(
            hb, HDIM, up_w + (size_t)l * ISZ * HDIM, HDIM, ub, ISZ, 0, HDIM, ub);
        gemm_r<2, u16><<<dim3(64, 4, 1), 512, LDSR, stream>>>(
            hb, HDIM, gate_w + (size_t)l * ISZ * HDIM, HDIM, pb, ISZ, 0, HDIM, ub);
        gemm_r<0, float><<<dim3(16, 4, 4), 512, LDSR, stream>>>(
            pb, ISZ, down_w + (size_t)l * HDIM * ISZ, ISZ, P, HDIM, s2048, 2048, ub);
        add_rmsnorm<<<T_SEQ, 256, 0, stream>>>(x, P, ln_post + l * HDIM, 4, s2048);
    }
    rmsnorm_bf16<<<T_SEQ, 256, 0, stream>>>(x, ln_f, hb);
    gemm_r<1, float><<<dim3(250, 4, 1), 512, LDSR, stream>>>(
        hb, HDIM, emb, HDIM, logits, NVOC, 0, HDIM, ub);
}

// Round 14
// 783.887 us; speedup vs baseline: 1.2111x; 1.2111x over previous
//
#include <hip/hip_runtime.h>
#include <hip/hip_bf16.h>
#include <math.h>

typedef unsigned short u16;
typedef __attribute__((ext_vector_type(8))) short bf16x8;
typedef __attribute__((ext_vector_type(4))) float f32x4;
typedef __attribute__((ext_vector_type(4))) u16 u16x4;
typedef __attribute__((ext_vector_type(4))) unsigned u32x4;

#define T_SEQ 1024
#define HDIM  2048
#define NHEAD 8
#define NKVH  4
#define HSZ   256
#define ISZ   8192
#define NVOC  32000

#define GLDS(src, dst) __builtin_amdgcn_global_load_lds( \
    (const __attribute__((address_space(1))) void*)(src), \
    (__attribute__((address_space(3))) void*)(dst), 16, 0, 0)

__device__ __forceinline__ u16 f2bf(float f) {
    union { float f; unsigned u; } v; v.f = f;
    return (u16)((v.u + 0x7fffu + ((v.u >> 16) & 1u)) >> 16);
}
__device__ __forceinline__ float bf2f(u16 h) {
    union { unsigned u; float f; } v; v.u = (unsigned)h << 16; return v.f;
}

__device__ __forceinline__ unsigned cvt_pk_bf16(float a, float b) {
    unsigned r;
    asm("v_cvt_pk_bf16_f32 %0, %1, %2" : "=v"(r) : "v"(a), "v"(b));
    return r;
}

__device__ __forceinline__ float fast_tanh(float x) {
    float e = __expf(-2.0f * fabsf(x));
    float t = (1.0f - e) / (1.0f + e);
    return copysignf(t, x);
}

__device__ __forceinline__ f32x4 mfma16(bf16x8 a, bf16x8 b, f32x4 c) {
    return __builtin_amdgcn_mfma_f32_16x16x32_bf16(a, b, c, 0, 0, 0);
}

// ============================================================================
// gemm_f (r10/r12-verified core): C = A[M,K](bf16) * B[N,K](f32, cvt@read)^T
// BM=256 BN=128 BK=64, 512 thr = 8 waves (4M x 2N), per-wave 64x64.
// 2 slots x (A bf16 32K + B f32 32K) = 128KB LDS. Ledger: 8 DMA ops/K-tile,
// top vmcnt(8) (never 0 mid-loop), stage(kt+2) after post-compute barrier.
// Swizzle: A 8-granule key r&7; B f32 16-granule key r&15, read slot G^fr.
// EPI: 0=f32 copy, 1=tanh-cap-30, 2=bf16(gelu_tanh(acc)*UP[idx]).
// blockIdx.z = split-K (A,B advance z*K; C advances z*sC).
// ============================================================================
template<int EPI, typename CT>
__global__ __launch_bounds__(512, 1)
void gemm_f(const u16* __restrict__ A, int lda,
            const float* __restrict__ B, int ldb,
            CT* __restrict__ C, int ldc, long sC, int K,
            const float* __restrict__ UP)
{
    extern __shared__ char lds[];   // 2 * 65536 bytes
    const int t = threadIdx.x;
    const int lane = t & 63, wid = t >> 6;
    const int z = blockIdx.z;
    A += (long)z * K;
    B += (long)z * K;
    C += (long)z * sC;

    const int nwg = gridDim.x * gridDim.y;
    int flat = blockIdx.y * gridDim.x + blockIdx.x;
    {
        const int q = nwg >> 3, r = nwg & 7;
        const int xcd = flat & 7, loc = flat >> 3;
        flat = (xcd < r ? xcd * (q + 1) : r * (q + 1) + (xcd - r) * q) + loc;
    }
    const int gm = gridDim.y;
    const long m0 = (long)(flat % gm) * 256;
    const long n0 = (long)(flat / gm) * 128;

    const int ar = t >> 3;
    const int asl = ((t & 7) ^ (ar & 7)) * 8;          // bf16 elems
    const u16* gA0 = A + (m0 + ar)       * (long)lda + asl;
    const u16* gA1 = A + (m0 + 64 + ar)  * (long)lda + asl;
    const u16* gA2 = A + (m0 + 128 + ar) * (long)lda + asl;
    const u16* gA3 = A + (m0 + 192 + ar) * (long)lda + asl;
    const int br = t >> 4;
    const int bsl = ((t & 15) ^ (br & 15)) * 4;        // f32 elems
    const float* gB0 = B + (n0 + br)      * (long)ldb + bsl;
    const float* gB1 = B + (n0 + 32 + br) * (long)ldb + bsl;
    const float* gB2 = B + (n0 + 64 + br) * (long)ldb + bsl;
    const float* gB3 = B + (n0 + 96 + br) * (long)ldb + bsl;

    auto stage = [&](int kt) {
        const long ko = (long)kt * 64;
        char* d = lds + (kt & 1) * 65536 + t * 16;
        GLDS(gA0 + ko, d);
        GLDS(gA1 + ko, d + 8192);
        GLDS(gA2 + ko, d + 16384);
        GLDS(gA3 + ko, d + 24576);
        GLDS(gB0 + ko, d + 32768);
        GLDS(gB1 + ko, d + 40960);
        GLDS(gB2 + ko, d + 49152);
        GLDS(gB3 + ko, d + 57344);
    };

    f32x4 acc[4][4] = {};
    const int fr = lane & 15, kq = lane >> 4;
    const int wm = wid >> 1, wn = wid & 1;
    const int ps0 = ((kq)     ^ (fr & 7)) * 8;
    const int ps1 = ((4 + kq) ^ (fr & 7)) * 8;

    const int KT = K >> 6;
    stage(0);
    stage(1);

    for (int kt = 0; kt < KT; ++kt) {
        if (kt < KT - 1) asm volatile("s_waitcnt vmcnt(8)" ::: "memory");
        else             asm volatile("s_waitcnt vmcnt(0)" ::: "memory");
        __builtin_amdgcn_s_barrier();

        const u16*   As = (const u16*)(lds + (kt & 1) * 65536);
        const float* Bs = (const float*)(lds + (kt & 1) * 65536 + 32768);
        const int arow = wm * 64 + fr;
        const int brow = wn * 64 + fr;

        #pragma unroll
        for (int kk = 0; kk < 2; ++kk) {
            const int ps = kk ? ps1 : ps0;
            const int G = 8 * kk + 2 * kq;
            const int sa = G ^ fr, sb = (G + 1) ^ fr;
            bf16x8 af[4], bfv[4];
            #pragma unroll
            for (int mi = 0; mi < 4; ++mi)
                af[mi] = *(const bf16x8*)(As + (arow + mi * 16) * 64 + ps);
            #pragma unroll
            for (int ni = 0; ni < 4; ++ni) {
                const float* rp = Bs + (brow + ni * 16) * 64;
                f32x4 v0 = *(const f32x4*)(rp + sa * 4);
                f32x4 v1 = *(const f32x4*)(rp + sb * 4);
                u32x4 bw;
                bw.x = cvt_pk_bf16(v0.x, v0.y);
                bw.y = cvt_pk_bf16(v0.z, v0.w);
                bw.z = cvt_pk_bf16(v1.x, v1.y);
                bw.w = cvt_pk_bf16(v1.z, v1.w);
                bfv[ni] = __builtin_bit_cast(bf16x8, bw);
            }
            __builtin_amdgcn_s_setprio(1);
            #pragma unroll
            for (int mi = 0; mi < 4; ++mi)
                #pragma unroll
                for (int ni = 0; ni < 4; ++ni)
                    acc[mi][ni] = mfma16(af[mi], bfv[ni], acc[mi][ni]);
            __builtin_amdgcn_s_setprio(0);
        }
        __builtin_amdgcn_s_barrier();
        if (kt + 2 < KT) stage(kt + 2);
    }

    const int crb = kq * 4, ccol = fr;
    #pragma unroll
    for (int mi = 0; mi < 4; ++mi) {
        #pragma unroll
        for (int rr = 0; rr < 4; ++rr) {
            const long row = m0 + wm * 64 + mi * 16 + crb + rr;
            CT* cp = C + row * ldc + n0 + wn * 64 + ccol;
            #pragma unroll
            for (int ni = 0; ni < 4; ++ni) {
                float v = acc[mi][ni][rr];
                if constexpr (EPI == 1) {
                    cp[ni * 16] = (CT)(fast_tanh(v * (1.0f / 30.0f)) * 30.0f);
                } else if constexpr (EPI == 2) {
                    const float* upp = UP + row * (long)ldc + n0 + wn * 64 + ccol;
                    const float tt = fast_tanh(0.79788456f * (v + 0.044715f * v * v * v));
                    const float g = 0.5f * v * (1.0f + tt);
                    ((u16*)cp)[ni * 16] = f2bf(g * upp[ni * 16]);
                } else {
                    cp[ni * 16] = (CT)v;
                }
            }
        }
    }
}

// ---- 128x128 GEMM for attention, with mask-skip / K-trim ----
template<int EPI, typename CT>
__global__ __launch_bounds__(256)
void gemm_bt(const u16* __restrict__ A, int lda, long sA,
             const u16* __restrict__ B, int ldb, long sB, int bshift,
             CT* __restrict__ C, int ldc, long sC, int K,
             int swin, int tflag)
{
    __shared__ u16 As[128 * 32];
    __shared__ u16 Bs[128 * 32];
    const int tid = threadIdx.x;
    const int lane = tid & 63, wid = tid >> 6;
    const int z = blockIdx.z;
    A += (long)z * sA;
    B += (long)(z >> bshift) * sB;
    C += (long)z * sC;

    const int nwg = gridDim.x * gridDim.y;
    int flat = blockIdx.y * gridDim.x + blockIdx.x;
    {
        const int q = nwg >> 3, r = nwg & 7;
        const int xcd = flat & 7, loc = flat >> 3;
        flat = (xcd < r ? xcd * (q + 1) : r * (q + 1) + (xcd - r) * q) + loc;
    }
    const int gm = gridDim.y;
    const long m0 = (long)(flat % gm) * 128;
    const long n0 = (long)(flat / gm) * 128;

    if (swin > 0) {
        if (n0 > m0 + 127) return;
        if (m0 - (n0 + 127) >= swin) return;
    }
    int klo = 0, khi = K;
    if (tflag > 0) {
        const long hi = m0 + 128;
        if (hi < khi) khi = (int)hi;
        const long lo = m0 - (long)tflag + 1;
        klo = lo > 0 ? (int)(lo & ~31L) : 0;
    }

    f32x4 acc[4][4] = {};

    const int ar = tid >> 2, ac = (tid & 3) * 8;
    const u16* gA0 = A + (m0 + ar) * lda + ac;
    const u16* gB0 = B + (n0 + ar) * (long)ldb + ac;
    const long a64 = 64L * lda, b64 = 64L * ldb;

    const int fr = lane & 15, fk = (lane >> 4) * 8;
    const int wm = (wid >> 1) * 64, wn = (wid & 1) * 64;

    for (int k0 = klo; k0 < khi; k0 += 32) {
        GLDS(gA0 + k0,       &As[tid * 8]);
        GLDS(gA0 + a64 + k0, &As[2048 + tid * 8]);
        GLDS(gB0 + k0,       &Bs[tid * 8]);
        GLDS(gB0 + b64 + k0, &Bs[2048 + tid * 8]);
        __syncthreads();
        bf16x8 af[4], bfv[4];
        #pragma unroll
        for (int mi = 0; mi < 4; ++mi)
            af[mi] = *(const bf16x8*)(&As[(wm + mi * 16 + fr) * 32 + fk]);
        #pragma unroll
        for (int ni = 0; ni < 4; ++ni)
            bfv[ni] = *(const bf16x8*)(&Bs[(wn + ni * 16 + fr) * 32 + fk]);
        #pragma unroll
        for (int mi = 0; mi < 4; ++mi)
            #pragma unroll
            for (int ni = 0; ni < 4; ++ni)
                acc[mi][ni] = mfma16(af[mi], bfv[ni], acc[mi][ni]);
        __syncthreads();
    }

    const int crb = (lane >> 4) * 4, ccol = lane & 15;
    #pragma unroll
    for (int mi = 0; mi < 4; ++mi) {
        #pragma unroll
        for (int rr = 0; rr < 4; ++rr) {
            const long row = m0 + wm + mi * 16 + crb + rr;
            CT* cp = C + row * ldc + n0 + wn + ccol;
            #pragma unroll
            for (int ni = 0; ni < 4; ++ni) {
                float v = acc[mi][ni][rr];
                if (EPI == 1) v = fast_tanh(v * (1.0f / 30.0f)) * 30.0f;
                if constexpr (sizeof(CT) == 2) cp[ni * 16] = f2bf(v);
                else                           cp[ni * 16] = v;
            }
        }
    }
}

// ---- embedding lookup * sqrt(H) ----
__global__ __launch_bounds__(256)
void embed_scale(const int* __restrict__ tok, const float* __restrict__ emb,
                 float* __restrict__ x)
{
    const int t = blockIdx.x, tid = threadIdx.x;
    const long src = (long)tok[t] * HDIM;
    f32x4 a = *(const f32x4*)(emb + src + tid * 8);
    f32x4 b = *(const f32x4*)(emb + src + tid * 8 + 4);
    a *= 45.254834f; b *= 45.254834f;
    *(f32x4*)(x + (long)t * HDIM + tid * 8) = a;
    *(f32x4*)(x + (long)t * HDIM + tid * 8 + 4) = b;
}

__device__ __forceinline__ float block_sum(float v, float* red) {
    #pragma unroll
    for (int o = 32; o; o >>= 1) v += __shfl_xor(v, o);
    const int tid = threadIdx.x;
    if ((tid & 63) == 0) red[tid >> 6] = v;
    __syncthreads();
    return red[0] + red[1] + red[2] + red[3];
}

// ---- rmsnorm (f32 in) -> bf16 out ----
__global__ __launch_bounds__(256)
void rmsnorm_bf16(const float* __restrict__ x, const float* __restrict__ w,
                  u16* __restrict__ out)
{
    __shared__ float red[4];
    const int t = blockIdx.x, tid = threadIdx.x;
    const float* row = x + (long)t * HDIM;
    f32x4 a = *(const f32x4*)(row + tid * 8);
    f32x4 b = *(const f32x4*)(row + tid * 8 + 4);
    float ss = a.x*a.x + a.y*a.y + a.z*a.z + a.w*a.w
             + b.x*b.x + b.y*b.y + b.z*b.z + b.w*b.w;
    ss = block_sum(ss, red);
    const float r = rsqrtf(ss * (1.0f / HDIM) + 1e-6f);
    f32x4 wa = *(const f32x4*)(w + tid * 8);
    f32x4 wb = *(const f32x4*)(w + tid * 8 + 4);
    u16x4 o0, o1;
    o0.x = f2bf(a.x * r * (1.0f + wa.x)); o0.y = f2bf(a.y * r * (1.0f + wa.y));
    o0.z = f2bf(a.z * r * (1.0f + wa.z)); o0.w = f2bf(a.w * r * (1.0f + wa.w));
    o1.x = f2bf(b.x * r * (1.0f + wb.x)); o1.y = f2bf(b.y * r * (1.0f + wb.y));
    o1.z = f2bf(b.z * r * (1.0f + wb.z)); o1.w = f2bf(b.w * r * (1.0f + wb.w));
    *(u16x4*)(out + (long)t * HDIM + tid * 8) = o0;
    *(u16x4*)(out + (long)t * HDIM + tid * 8 + 4) = o1;
}

// ---- fused: x += rmsnorm(sum_s y[s], w1); out = bf16(rmsnorm(x, w2)) ----
__global__ __launch_bounds__(256)
void add_rms_rms(float* __restrict__ x, const float* __restrict__ y,
                 const float* __restrict__ w1, const float* __restrict__ w2,
                 u16* __restrict__ out, int nsplit, long stride)
{
    __shared__ float red[4];
    const int t = blockIdx.x, tid = threadIdx.x;
    const float* yr = y + (long)t * HDIM;
    f32x4 a = *(const f32x4*)(yr + tid * 8);
    f32x4 b = *(const f32x4*)(yr + tid * 8 + 4);
    for (int s = 1; s < nsplit; ++s) {
        a += *(const f32x4*)(yr + s * stride + tid * 8);
        b += *(const f32x4*)(yr + s * stride + tid * 8 + 4);
    }
    float ss = a.x*a.x + a.y*a.y + a.z*a.z + a.w*a.w
             + b.x*b.x + b.y*b.y + b.z*b.z + b.w*b.w;
    ss = block_sum(ss, red);
    const float r1 = rsqrtf(ss * (1.0f / HDIM) + 1e-6f);
    f32x4 wa = *(const f32x4*)(w1 + tid * 8);
    f32x4 wb = *(const f32x4*)(w1 + tid * 8 + 4);
    float* xr = x + (long)t * HDIM;
    f32x4 xa = *(const f32x4*)(xr + tid * 8);
    f32x4 xb = *(const f32x4*)(xr + tid * 8 + 4);
    xa.x += a.x * r1 * (1.0f + wa.x); xa.y += a.y * r1 * (1.0f + wa.y);
    xa.z += a.z * r1 * (1.0f + wa.z); xa.w += a.w * r1 * (1.0f + wa.w);
    xb.x += b.x * r1 * (1.0f + wb.x); xb.y += b.y * r1 * (1.0f + wb.y);
    xb.z += b.z * r1 * (1.0f + wb.z); xb.w += b.w * r1 * (1.0f + wb.w);
    *(f32x4*)(xr + tid * 8) = xa;
    *(f32x4*)(xr + tid * 8 + 4) = xb;
    __syncthreads();   // red[] reuse hazard
    float ss2 = xa.x*xa.x + xa.y*xa.y + xa.z*xa.z + xa.w*xa.w
              + xb.x*xb.x + xb.y*xb.y + xb.z*xb.z + xb.w*xb.w;
    ss2 = block_sum(ss2, red);
    const float r2 = rsqrtf(ss2 * (1.0f / HDIM) + 1e-6f);
    f32x4 va = *(const f32x4*)(w2 + tid * 8);
    f32x4 vb = *(const f32x4*)(w2 + tid * 8 + 4);
    u16x4 o0, o1;
    o0.x = f2bf(xa.x * r2 * (1.0f + va.x)); o0.y = f2bf(xa.y * r2 * (1.0f + va.y));
    o0.z = f2bf(xa.z * r2 * (1.0f + va.z)); o0.w = f2bf(xa.w * r2 * (1.0f + va.w));
    o1.x = f2bf(xb.x * r2 * (1.0f + vb.x)); o1.y = f2bf(xb.y * r2 * (1.0f + vb.y));
    o1.z = f2bf(xb.z * r2 * (1.0f + vb.z)); o1.w = f2bf(xb.w * r2 * (1.0f + vb.w));
    *(u16x4*)(out + (long)t * HDIM + tid * 8) = o0;
    *(u16x4*)(out + (long)t * HDIM + tid * 8 + 4) = o1;
}

#define QKV_STRIDE (1024L * 4096)

// ---- rope + split (qkv = sum of 2 split-K slices): q(bf16,*SCALE), k(bf16) ----
__global__ __launch_bounds__(256)
void qkv_post(const float* __restrict__ qkv, u16* __restrict__ qb,
              u16* __restrict__ kb)
{
    const int t = blockIdx.x, tid = threadIdx.x;
    const float* row = qkv + (long)t * 4096;
    const float ft = (float)t;
    #pragma unroll
    for (int it = 0; it < 4; ++it) {
        const int p = tid + it * 256;
        const int nh = p >> 7, d = p & 127;
        const float inv = powf(10000.0f, -(float)d * (1.0f / 128.0f));
        const float ang = ft * inv;
        const float c = cosf(ang), s = sinf(ang);
        const int i1 = nh * 256 + d, i2 = i1 + 128;
        const float x1 = row[i1] + row[i1 + QKV_STRIDE];
        const float x2 = row[i2] + row[i2 + QKV_STRIDE];
        const long ob = ((long)nh * T_SEQ + t) * HSZ;
        qb[ob + d]       = f2bf((x1 * c - x2 * s) * 0.0625f);
        qb[ob + 128 + d] = f2bf((x1 * s + x2 * c) * 0.0625f);
    }
    #pragma unroll
    for (int it = 0; it < 2; ++it) {
        const int p = tid + it * 256;
        const int kv = p >> 7, d = p & 127;
        const float inv = powf(10000.0f, -(float)d * (1.0f / 128.0f));
        const float ang = ft * inv;
        const float c = cosf(ang), s = sinf(ang);
        const int i1 = 2048 + kv * 256 + d, i2 = i1 + 128;
        const float x1 = row[i1] + row[i1 + QKV_STRIDE];
        const float x2 = row[i2] + row[i2 + QKV_STRIDE];
        const long ob = ((long)kv * T_SEQ + t) * HSZ;
        kb[ob + d]       = f2bf(x1 * c - x2 * s);
        kb[ob + 128 + d] = f2bf(x1 * s + x2 * c);
    }
}

// ---- V (summed 2 slices) -> vT[kv][d][t] bf16, tiled transpose ----
__global__ __launch_bounds__(256)
void v_transpose(const float* __restrict__ qkvb, u16* __restrict__ vT)
{
    __shared__ u16 tile[64][65];
    const int t0 = blockIdx.x * 64, d0 = blockIdx.y * 64, kv = blockIdx.z;
    const int lane = threadIdx.x & 63, w = threadIdx.x >> 6;
    #pragma unroll
    for (int i = 0; i < 16; ++i) {
        const int t = w * 16 + i;
        const long idx = (long)(t0 + t) * 4096 + 3072 + kv * 256 + d0 + lane;
        tile[t][lane] = f2bf(qkvb[idx] + qkvb[idx + QKV_STRIDE]);
    }
    __syncthreads();
    #pragma unroll
    for (int i = 0; i < 16; ++i) {
        const int d = w * 16 + i;
        vT[((long)kv * HSZ + d0 + d) * T_SEQ + t0 + lane] = tile[lane][d];
    }
}

// ---- softcap + mask + softmax -> bf16 probs ----
__global__ __launch_bounds__(256)
void softmax_mask(const float* __restrict__ sc, u16* __restrict__ pr, int win)
{
    __shared__ float redm[4], reds[4];
    const int i = blockIdx.x, h = blockIdx.y, tid = threadIdx.x;
    const long base = ((long)h * T_SEQ + i) * T_SEQ;
    f32x4 sv = *(const f32x4*)(sc + base + tid * 4);
    float vals[4];
    #pragma unroll
    for (int j = 0; j < 4; ++j) {
        const int col = tid * 4 + j;
        const float s = fast_tanh(sv[j] * 0.02f) * 50.0f;
        const bool valid = (col <= i) && ((i - col) < win);
        vals[j] = valid ? s : -3.0e38f;
    }
    float m = fmaxf(fmaxf(vals[0], vals[1]), fmaxf(vals[2], vals[3]));
    #pragma unroll
    for (int o = 32; o; o >>= 1) m = fmaxf(m, __shfl_xor(m, o));
    if ((tid & 63) == 0) redm[tid >> 6] = m;
    __syncthreads();
    m = fmaxf(fmaxf(redm[0], redm[1]), fmaxf(redm[2], redm[3]));
    float sum = 0.0f;
    #pragma unroll
    for (int j = 0; j < 4; ++j) { vals[j] = __expf(vals[j] - m); sum += vals[j]; }
    #pragma unroll
    for (int o = 32; o; o >>= 1) sum += __shfl_xor(sum, o);
    if ((tid & 63) == 0) reds[tid >> 6] = sum;
    __syncthreads();
    sum = reds[0] + reds[1] + reds[2] + reds[3];
    const float inv = 1.0f / sum;
    u16x4 o4;
    #pragma unroll
    for (int j = 0; j < 4; ++j) o4[j] = f2bf(vals[j] * inv);
    *(u16x4*)(pr + base + tid * 4) = o4;
}

extern "C" void kernel_launch(void* const* d_in, const int* in_sizes, int n_in,
                              void* d_out, int out_size, void* d_ws, size_t ws_size,
                              hipStream_t stream)
{
    (void)in_sizes; (void)n_in; (void)out_size; (void)ws_size;
    const int*   tokens = (const int*)  d_in[0];
    const float* emb    = (const float*)d_in[1];
    const float* qkv_w  = (const float*)d_in[2];
    const float* o_w    = (const float*)d_in[3];
    const float* gate_w = (const float*)d_in[4];
    const float* up_w   = (const float*)d_in[5];
    const float* down_w = (const float*)d_in[6];
    const float* ln_in  = (const float*)d_in[7];
    const float* ln_pa  = (const float*)d_in[8];
    const float* ln_pre = (const float*)d_in[9];
    const float* ln_post= (const float*)d_in[10];
    const float* ln_f   = (const float*)d_in[11];
    float* logits = (float*)d_out;

    char* base = (char*)d_ws;
    size_t off = 0;
    auto alloc = [&](size_t b) { char* p = base + off; off += (b + 255) & ~(size_t)255; return p; };

    float* x    = (float*)alloc((size_t)T_SEQ * HDIM * 4);
    u16*   hb   = (u16*)  alloc((size_t)T_SEQ * HDIM * 2);
    u16*   qb   = (u16*)  alloc((size_t)NHEAD * T_SEQ * HSZ * 2);
    u16*   kb   = (u16*)  alloc((size_t)NKVH * T_SEQ * HSZ * 2);
    u16*   vT   = (u16*)  alloc((size_t)NKVH * HSZ * T_SEQ * 2);
    u16*   ao   = (u16*)  alloc((size_t)T_SEQ * HDIM * 2);
    u16*   pb   = (u16*)  alloc((size_t)T_SEQ * ISZ * 2);
    // big aliased region (64MB), sequential lifetimes:
    //  qkv partials[2] -> sc+pr -> o partials[4] -> ub -> down partials[4]
    char*  big  = alloc((size_t)2 * T_SEQ * ISZ * 4);
    float* P    = (float*)big;
    float* sc   = (float*)big;
    u16*   pr   = (u16*)(big + (size_t)NHEAD * T_SEQ * T_SEQ * 4);
    float* ub   = (float*)(big + (size_t)T_SEQ * ISZ * 4);

    const size_t LDSF = 2 * 65536;   // gemm_f dynamic LDS
    const long s2048 = 1024L * 2048;
    const int BIGWIN = 1 << 29;

    embed_scale<<<T_SEQ, 256, 0, stream>>>(tokens, emb, x);
    for (int l = 0; l < 2; ++l) {
        const int win = (l == 0) ? 512 : BIGWIN;
        if (l == 0)
            rmsnorm_bf16<<<T_SEQ, 256, 0, stream>>>(x, ln_in, hb);
        gemm_f<0, float><<<dim3(32, 4, 2), 512, LDSF, stream>>>(
            hb, HDIM, qkv_w + (size_t)l * 4096 * HDIM, HDIM, P, 4096, QKV_STRIDE, 1024, ub);
        qkv_post<<<T_SEQ, 256, 0, stream>>>(P, qb, kb);
        v_transpose<<<dim3(16, 4, 4), 256, 0, stream>>>(P, vT);
        gemm_bt<0, float><<<dim3(8, 8, NHEAD), 256, 0, stream>>>(
            qb, HSZ, (long)T_SEQ * HSZ, kb, HSZ, (long)T_SEQ * HSZ, 1,
            sc, T_SEQ, (long)T_SEQ * T_SEQ, HSZ, win, 0);
        softmax_mask<<<dim3(T_SEQ, NHEAD, 1), 256, 0, stream>>>(
            sc, pr, l == 0 ? 512 : (1 << 30));
        gemm_bt<0, u16><<<dim3(2, 8, NHEAD), 256, 0, stream>>>(
            pr, T_SEQ, (long)T_SEQ * T_SEQ, vT, T_SEQ, (long)HSZ * T_SEQ, 1,
            ao, HDIM, (long)HSZ, T_SEQ, 0, win);
        gemm_f<0, float><<<dim3(16, 4, 4), 512, LDSF, stream>>>(
            ao, HDIM, o_w + (size_t)l * HDIM * HDIM, HDIM, P, HDIM, s2048, 512, ub);
        // fused: x += rms(P, ln_pa); hb = bf16(rms(x, ln_pre))
        add_rms_rms<<<T_SEQ, 256, 0, stream>>>(
            x, P, ln_pa + l * HDIM, ln_pre + l * HDIM, hb, 4, s2048);
        // up first (f32 -> ub), then gate with fused gelu(acc)*ub -> pb (bf16)
        gemm_f<0, float><<<dim3(64, 4, 1), 512, LDSF, stream>>>(
            hb, HDIM, up_w + (size_t)l * ISZ * HDIM, HDIM, ub, ISZ, 0, HDIM, ub);
        gemm_f<2, u16><<<dim3(64, 4, 1), 512, LDSF, stream>>>(
            hb, HDIM, gate_w + (size_t)l * ISZ * HDIM, HDIM, pb, ISZ, 0, HDIM, ub);
        gemm_f<0, float><<<dim3(16, 4, 4), 512, LDSF, stream>>>(
            pb, ISZ, down_w + (size_t)l * HDIM * ISZ, ISZ, P, HDIM, s2048, 2048, ub);
        // fused: x += rms(P, ln_post); hb = bf16(rms(x, next-norm))
        const float* w2 = (l == 0) ? (ln_in + HDIM) : ln_f;
        add_rms_rms<<<T_SEQ, 256, 0, stream>>>(
            x, P, ln_post + l * HDIM, w2, hb, 4, s2048);
    }
    gemm_f<1, float><<<dim3(250, 4, 1), 512, LDSF, stream>>>(
        hb, HDIM, emb, HDIM, logits, NVOC, 0, HDIM, ub);
}